// Round 3
// baseline (513.268 us; speedup 1.0000x reference)
//
#include <hip/hip_runtime.h>
#include <hip/hip_bf16.h>

#define C_CH 4096
#define D_DIM 128
#define CHUNK 1024   // ids per block in hist/place kernels

typedef float f32x2 __attribute__((ext_vector_type(2)));

// ---------------- sort path: block-histogram counting sort, no global atomics
// ---------------- except 524K atomicMin for first-occurrence ----------------

__global__ __launch_bounds__(256) void init_first_kernel(int* first, int B) {
    int i = blockIdx.x * blockDim.x + threadIdx.x;
    if (i < C_CH) first[i] = B - 1;
}

// K1: per-block LDS histogram -> hist[b][c]; global atomicMin for first index
__global__ __launch_bounds__(256) void hist_kernel(const int* __restrict__ ids,
                                                   int* __restrict__ hist,
                                                   int* __restrict__ first, int B) {
    __shared__ int h[C_CH];
    int tid = threadIdx.x, b = blockIdx.x;
    for (int k = tid; k < C_CH; k += 256) h[k] = 0;
    __syncthreads();
    int base = b * CHUNK + tid * 4;
    if (base + 3 < B) {
        int4 v = ((const int4*)ids)[b * 256 + tid];
        atomicAdd(&h[v.x], 1); atomicAdd(&h[v.y], 1);
        atomicAdd(&h[v.z], 1); atomicAdd(&h[v.w], 1);
        atomicMin(&first[v.x], base + 0);
        atomicMin(&first[v.y], base + 1);
        atomicMin(&first[v.z], base + 2);
        atomicMin(&first[v.w], base + 3);
    } else {
        for (int k = 0; k < 4; ++k) {
            int i = base + k;
            if (i < B) { int c = ids[i]; atomicAdd(&h[c], 1); atomicMin(&first[c], i); }
        }
    }
    __syncthreads();
    int* hrow = hist + (size_t)b * C_CH;
    for (int k = tid; k < C_CH; k += 256) hrow[k] = h[k];
}

// K2a: cnt[c] = sum_b hist[b][c]  (thread per channel, coalesced rows)
__global__ __launch_bounds__(256) void colsum_kernel(const int* __restrict__ hist,
                                                     int* __restrict__ cnt, int nblk) {
    int c = blockIdx.x * blockDim.x + threadIdx.x;
    if (c >= C_CH) return;
    int s = 0;
    for (int b = 0; b < nblk; ++b) s += hist[(size_t)b * C_CH + c];
    cnt[c] = s;
}

// K2b: exclusive prefix over 4096 counts; one block of 1024 threads, 4 elems each
__global__ void scan_kernel(const int* __restrict__ cnt, int* offs) {
    __shared__ int wtot[16];
    int tid  = threadIdx.x;
    int lane = tid & 63;
    int wave = tid >> 6;
    int base = tid * 4;
    int v0 = cnt[base + 0], v1 = cnt[base + 1], v2 = cnt[base + 2], v3 = cnt[base + 3];
    int s = v0 + v1 + v2 + v3;
    int inc = s;
    for (int off = 1; off < 64; off <<= 1) {
        int n = __shfl_up(inc, off, 64);
        if (lane >= off) inc += n;
    }
    if (lane == 63) wtot[wave] = inc;
    __syncthreads();
    if (wave == 0) {
        int t = (lane < 16) ? wtot[lane] : 0;
        int ts = t;
        for (int off = 1; off < 16; off <<= 1) {
            int n = __shfl_up(ts, off, 64);
            if (lane >= off) ts += n;
        }
        if (lane < 16) wtot[lane] = ts - t;
    }
    __syncthreads();
    int run = wtot[wave] + (inc - s);
    offs[base + 0] = run; run += v0;
    offs[base + 1] = run; run += v1;
    offs[base + 2] = run; run += v2;
    offs[base + 3] = run; run += v3;
    if (tid == 1023) offs[C_CH] = run;   // == B
}

// K2c: hist[b][c] <- offs[c] + sum_{b'<b} hist[b'][c]   (per-block placement base)
__global__ __launch_bounds__(256) void base_kernel(int* __restrict__ hist,
                                                   const int* __restrict__ offs, int nblk) {
    int c = blockIdx.x * blockDim.x + threadIdx.x;
    if (c >= C_CH) return;
    int run = offs[c];
    for (int b = 0; b < nblk; ++b) {
        size_t idx = (size_t)b * C_CH + c;
        int old = hist[idx];
        hist[idx] = run;
        run += old;
    }
}

// K3: place row indices using LDS cursors seeded from per-block bases. No global atomics.
__global__ __launch_bounds__(256) void place_kernel(const int* __restrict__ ids,
                                                    const int* __restrict__ hist,
                                                    int* __restrict__ order, int B) {
    __shared__ int cur[C_CH];
    int tid = threadIdx.x, b = blockIdx.x;
    const int* hrow = hist + (size_t)b * C_CH;
    for (int k = tid; k < C_CH; k += 256) cur[k] = hrow[k];
    __syncthreads();
    int base = b * CHUNK + tid * 4;
    if (base + 3 < B) {
        int4 v = ((const int4*)ids)[b * 256 + tid];
        int p0 = atomicAdd(&cur[v.x], 1);
        int p1 = atomicAdd(&cur[v.y], 1);
        int p2 = atomicAdd(&cur[v.z], 1);
        int p3 = atomicAdd(&cur[v.w], 1);
        order[p0] = base + 0;
        order[p1] = base + 1;
        order[p2] = base + 2;
        order[p3] = base + 3;
    } else {
        for (int k = 0; k < 4; ++k) {
            int i = base + k;
            if (i < B) { int pos = atomicAdd(&cur[ids[i]], 1); order[pos] = i; }
        }
    }
}

// K4: one WAVE per channel; lane l owns columns (2l, 2l+1) via f32x2.
// Each row read = one 512B wave-level dwordx2 load; 8 rows in flight; nontemporal.
__global__ __launch_bounds__(256) void reduce_kernel(
        const float* __restrict__ z, const int* __restrict__ order,
        const int* __restrict__ offs, const int* __restrict__ first,
        const int* __restrict__ y, float* __restrict__ out, int B) {
    int w = blockIdx.x * 4 + (threadIdx.x >> 6);   // channel
    int lane = threadIdx.x & 63;
    if (w >= C_CH) return;
    int beg = offs[w], end = offs[w + 1];
    const f32x2* z2 = (const f32x2*)z;
    float ax = 0.f, ay = 0.f;
    int r = beg;
    for (; r + 8 <= end; r += 8) {
        int i0 = order[r + 0], i1 = order[r + 1], i2 = order[r + 2], i3 = order[r + 3];
        int i4 = order[r + 4], i5 = order[r + 5], i6 = order[r + 6], i7 = order[r + 7];
        f32x2 v0 = __builtin_nontemporal_load(&z2[(size_t)i0 * 64 + lane]);
        f32x2 v1 = __builtin_nontemporal_load(&z2[(size_t)i1 * 64 + lane]);
        f32x2 v2 = __builtin_nontemporal_load(&z2[(size_t)i2 * 64 + lane]);
        f32x2 v3 = __builtin_nontemporal_load(&z2[(size_t)i3 * 64 + lane]);
        f32x2 v4 = __builtin_nontemporal_load(&z2[(size_t)i4 * 64 + lane]);
        f32x2 v5 = __builtin_nontemporal_load(&z2[(size_t)i5 * 64 + lane]);
        f32x2 v6 = __builtin_nontemporal_load(&z2[(size_t)i6 * 64 + lane]);
        f32x2 v7 = __builtin_nontemporal_load(&z2[(size_t)i7 * 64 + lane]);
        ax += ((v0.x + v1.x) + (v2.x + v3.x)) + ((v4.x + v5.x) + (v6.x + v7.x));
        ay += ((v0.y + v1.y) + (v2.y + v3.y)) + ((v4.y + v5.y) + (v6.y + v7.y));
    }
    for (; r < end; ++r) {
        f32x2 v = __builtin_nontemporal_load(&z2[(size_t)order[r] * 64 + lane]);
        ax += v.x; ay += v.y;
    }
    int cnt_c = end - beg;
    float inv = 1.f / (float)max(cnt_c, 1);
    f32x2 res; res.x = ax * inv; res.y = ay * inv;
    ((f32x2*)out)[(size_t)w * 64 + lane] = res;
    if (lane == 0) {
        int fi = min(first[w], B - 1);
        out[(size_t)C_CH * D_DIM + w] = (float)y[fi];
    }
}

// ---------------- fallback path (ws too small): direct fp atomics into d_out --------

__global__ void count_kernel(const int* __restrict__ ids, int* cnt, int* first, int B) {
    int i = blockIdx.x * blockDim.x + threadIdx.x;
    if (i < B) {
        int c = ids[i];
        atomicAdd(&cnt[c], 1);
        atomicMin(&first[c], i);
    }
}

__global__ void f_init(float* out, int* cnt, int* first, int B, int n) {
    int i = blockIdx.x * blockDim.x + threadIdx.x;
    if (i < n) out[i] = 0.f;
    if (i < C_CH) { cnt[i] = 0; first[i] = B - 1; }
}

__global__ void f_scatter(const float* __restrict__ z, const int* __restrict__ ids,
                          float* out, int B) {
    int t = blockIdx.x * blockDim.x + threadIdx.x;
    int row = t >> 5, q = t & 31;
    if (row < B) {
        float4 v = ((const float4*)z)[t];
        float* dst = out + (size_t)ids[row] * D_DIM + q * 4;
        unsafeAtomicAdd(dst + 0, v.x);
        unsafeAtomicAdd(dst + 1, v.y);
        unsafeAtomicAdd(dst + 2, v.z);
        unsafeAtomicAdd(dst + 3, v.w);
    }
}

__global__ void f_final(float* out, const int* __restrict__ cnt,
                        const int* __restrict__ first, const int* __restrict__ y) {
    int i = blockIdx.x * blockDim.x + threadIdx.x;
    if (i < C_CH * D_DIM) {
        int c = i >> 7;
        out[i] = out[i] / (float)max(cnt[c], 1);
    }
    if (i < C_CH) out[C_CH * D_DIM + i] = (float)y[first[i]];
}

// ---------------- launch ----------------

extern "C" void kernel_launch(void* const* d_in, const int* in_sizes, int n_in,
                              void* d_out, int out_size, void* d_ws, size_t ws_size,
                              hipStream_t stream) {
    const float* z   = (const float*)d_in[0];
    const int*   y   = (const int*)d_in[1];
    const int*   ids = (const int*)d_in[2];
    float* out = (float*)d_out;
    const int B = in_sizes[2];
    const int nblk = (B + CHUNK - 1) / CHUNK;

    // workspace layout (int elements)
    int* first = (int*)d_ws;                 // 4096
    int* cnt   = first + C_CH;               // 4096
    int* offs  = cnt + C_CH;                 // 4097 (+3 pad)
    int* order = (int*)d_ws + 16384;         // B
    int* hist  = order + B;                  // nblk * 4096
    size_t need = ((size_t)16384 + (size_t)B + (size_t)nblk * C_CH) * sizeof(int);

    if (ws_size >= need) {
        init_first_kernel<<<(C_CH + 255) / 256, 256, 0, stream>>>(first, B);
        hist_kernel<<<nblk, 256, 0, stream>>>(ids, hist, first, B);
        colsum_kernel<<<(C_CH + 255) / 256, 256, 0, stream>>>(hist, cnt, nblk);
        scan_kernel<<<1, 1024, 0, stream>>>(cnt, offs);
        base_kernel<<<(C_CH + 255) / 256, 256, 0, stream>>>(hist, offs, nblk);
        place_kernel<<<nblk, 256, 0, stream>>>(ids, hist, order, B);
        reduce_kernel<<<C_CH / 4, 256, 0, stream>>>(z, order, offs, first, y, out, B);
    } else {
        int n = C_CH * D_DIM;
        f_init<<<(n + 255) / 256, 256, 0, stream>>>(out, cnt, first, B, n);
        count_kernel<<<(B + 255) / 256, 256, 0, stream>>>(ids, cnt, first, B);
        long long t = (long long)B * 32;
        f_scatter<<<(int)((t + 255) / 256), 256, 0, stream>>>(z, ids, out, B);
        f_final<<<(n + 255) / 256, 256, 0, stream>>>(out, cnt, first, y);
    }
}